// Round 1
// 532.205 us; speedup vs baseline: 1.5388x; 1.5388x over previous
//
#include <hip/hip_runtime.h>
#include <hip/hip_bf16.h>

// ---------------- types & helpers ----------------

typedef __attribute__((ext_vector_type(8)))  short bf16x8;   // 8 bf16 = 4 VGPR
typedef __attribute__((ext_vector_type(16))) float f32x16;   // MFMA 32x32 acc
typedef __attribute__((ext_vector_type(4)))  float vf4;

__device__ __forceinline__ unsigned short f2bf(float x) {    // RNE fp32->bf16
  union { float f; unsigned u; } c; c.f = x;
  return (unsigned short)((c.u + 0x7fffu + ((c.u >> 16) & 1u)) >> 16);
}
__device__ __forceinline__ float bf2f(unsigned short u) {    // exact bf16->fp32
  union { unsigned u; float f; } c; c.u = ((unsigned)u) << 16;
  return c.f;
}

// ---------------- sentinel & dtype probes ----------------

__global__ void k_sentinel(unsigned short* __restrict__ out, int n) {
  int i = blockIdx.x * blockDim.x + threadIdx.x;
  if (i < n) out[i] = 0x3F00;
}

__global__ void k_ftype(const unsigned* __restrict__ p, int nwords, int* __restrict__ vflag) {
  __shared__ int red[256];
  int ok = 0;
  for (int i = threadIdx.x; i < nwords; i += 256) {
    unsigned lo = p[i] & 0xffffu;
    unsigned ef = (lo >> 7) & 0xffu;
    if (ef >= 115u && ef <= 140u) ok++;
  }
  red[threadIdx.x] = ok;
  __syncthreads();
  for (int s = 128; s > 0; s >>= 1) {
    if (threadIdx.x < s) red[threadIdx.x] += red[threadIdx.x + s];
    __syncthreads();
  }
  if (threadIdx.x == 0) *vflag = (red[0] < nwords / 2) ? 1 : 0;
}

__global__ void k_etype(const unsigned* __restrict__ p, int nwords, int* __restrict__ eflag) {
  __shared__ unsigned red[256];
  unsigned acc = 0;
  for (int i = threadIdx.x; i < nwords; i += 256)
    if (i & 1) acc |= p[i];
  red[threadIdx.x] = acc;
  __syncthreads();
  for (int s = 128; s > 0; s >>= 1) {
    if (threadIdx.x < s) red[threadIdx.x] |= red[threadIdx.x + s];
    __syncthreads();
  }
  if (threadIdx.x == 0) *eflag = (red[0] == 0u) ? 1 : 0;
}

// ---------------- preprocessing ----------------

__global__ void k_zero(float* __restrict__ deg, int* __restrict__ cnt, int n) {
  int i = blockIdx.x * blockDim.x + threadIdx.x;
  if (i < n) { deg[i] = 0.0f; cnt[i] = 0; }
}

__global__ void k_decode(const void* __restrict__ ei, const int* __restrict__ eflag,
                         int E, int N, int* __restrict__ rowi, int* __restrict__ coli,
                         float* __restrict__ deg, int* __restrict__ cnt) {
  int e = blockIdx.x * blockDim.x + threadIdx.x;
  if (e >= E) return;
  int f = *eflag;
  int r, c;
  if (f) {
    const long long* q = (const long long*)ei;
    r = (int)q[e]; c = (int)q[e + E];
  } else {
    const int* q = (const int*)ei;
    r = q[e]; c = q[e + E];
  }
  r = min(max(r, 0), N - 1);
  c = min(max(c, 0), N - 1);
  rowi[e] = r; coli[e] = c;
  atomicAdd(&deg[r], 1.0f);
  atomicAdd(&cnt[c], 1);
}

__global__ void k_dis(const float* __restrict__ deg, float* __restrict__ dis, int n) {
  int i = blockIdx.x * blockDim.x + threadIdx.x;
  if (i < n) {
    float d = deg[i];
    dis[i] = (d > 0.f) ? rsqrtf(d) : 0.f;
  }
}

__global__ void k_scan(const int* __restrict__ cnt, int* __restrict__ colPtr,
                       int* __restrict__ cursor, int n) {
  __shared__ int buf[2][256];
  __shared__ int carry;
  int t = threadIdx.x;
  if (t == 0) carry = 0;
  __syncthreads();
  for (int base = 0; base < n; base += 256) {
    int i = base + t;
    int v = (i < n) ? cnt[i] : 0;
    int sel = 0;
    buf[0][t] = v;
    __syncthreads();
    for (int off = 1; off < 256; off <<= 1) {
      int val = buf[sel][t];
      if (t >= off) val += buf[sel][t - off];
      buf[1 - sel][t] = val;
      sel = 1 - sel;
      __syncthreads();
    }
    int incl = carry + buf[sel][t];
    if (i < n) { colPtr[i + 1] = incl; cursor[i] = incl - v; }
    int total = buf[sel][255];
    __syncthreads();
    if (t == 0) carry += total;
    __syncthreads();
  }
  if (t == 0) colPtr[0] = 0;
}

__global__ void k_place(const int* __restrict__ rowi, const int* __restrict__ coli,
                        const float* __restrict__ dis, int* __restrict__ cursor,
                        int* __restrict__ srcRow, float* __restrict__ srcW, int E) {
  int e = blockIdx.x * blockDim.x + threadIdx.x;
  if (e >= E) return;
  int r = rowi[e], c = coli[e];
  float wv = -dis[r] * dis[c];
  int pos = atomicAdd(&cursor[c], 1);
  srcRow[pos] = r;
  srcW[pos] = wv;
}

__global__ void k_convert(const void* __restrict__ v, const int* __restrict__ vflag,
                          float* __restrict__ x, int n) {
  int i = blockIdx.x * blockDim.x + threadIdx.x;
  if (i >= n) return;
  if (*vflag) x[i] = ((const float*)v)[i];
  else        x[i] = __bfloat162float(((const __hip_bfloat16*)v)[i]);
}

// ---------------- propagation ----------------
// out[c,:] = alpha * sum_{e: col=c} w_e * z[row_e,:] + beta*base[c,:]
__global__ void k_prop(const float* __restrict__ z, const float* __restrict__ base,
                       float* __restrict__ out,
                       const int* __restrict__ colPtr, const int* __restrict__ srcRow,
                       const float* __restrict__ srcW,
                       int F, float alpha, float beta) {
  const int c = blockIdx.x;
  const int f = threadIdx.x;
  const int s = colPtr[c];
  const int e = colPtr[c + 1];
  float acc = 0.f;
  for (int j = s; j < e; j++)
    acc = fmaf(srcW[j], z[(size_t)srcRow[j] * F + f], acc);
  float vv = alpha * acc;
  if (base != nullptr) vv = fmaf(beta, base[(size_t)c * F + f], vv);
  out[(size_t)c * F + f] = vv;
}

// ---------------- MFMA GEMM ----------------
// C[N,Fo] = maybe_relu( [A0|A1|A2] @ W + b )
// A is fp32; split per element into hi+lo bf16 (a = hi + lo to ~2^-17 rel) and
// accumulate in fp32 MFMA: acc += A_hi*B_hi + A_lo*B_hi (+ A_hi*B_lo if W fp32).
// This matches the scalar-fp32 result far below the output tolerance.
//
// Tiling: block 64(M) x 128(N), BK=32, 4 waves as 2x2, each wave 32x64
// (2 n-frags of v_mfma_f32_32x32x16_bf16). LDS holds A/B tiles in
// "fragment-linear" order: frag f, lane l owns 16B at (f*64+l)*16 ->
// every ds_read_b128 / ds_write_b128 is lane-consecutive (no bank conflicts).
// NOTE on k-mapping: both A and B frags are staged with the SAME
// (group,j)->k bijection (k = kc*16 + (l>>5)*8 + j), so any HW-internal k
// permutation cancels; only the C/D layout must match HW:
//   col = lane&31, row = (reg&3) + 8*(reg>>2) + 4*(lane>>5)   [m74/m101]
__global__ __launch_bounds__(256, 2) void k_gemm_mfma(
    const float* __restrict__ A0, const float* __restrict__ A1,
    const float* __restrict__ A2,
    const void* __restrict__ W, const void* __restrict__ bias,
    const int* __restrict__ wflagp,
    int N, int Fi, int NQ, int Fo,
    float* __restrict__ outF, unsigned short* __restrict__ outB16,
    float* __restrict__ outB32, int relu) {
  __shared__ bf16x8 sAhi[4 * 64];   // 4 A-frags (2 m-blocks x 2 k-chunks)
  __shared__ bf16x8 sAlo[4 * 64];
  __shared__ bf16x8 sBhi[8 * 64];   // 8 B-frags (4 n-blocks x 2 k-chunks)
  __shared__ bf16x8 sBlo[8 * 64];   // only touched when wflag (fp32 weights)

  const int wflag = *wflagp;
  const int tid  = threadIdx.x;
  const int lane = tid & 63;
  const int wid  = tid >> 6;
  const int wm   = wid >> 1;              // wave row-half (0..1)
  const int wn   = wid & 1;               // wave col-half (0..1)
  const int n0   = blockIdx.x * 128;      // n-tiles fastest: blocks sharing the
  const int m0   = blockIdx.y * 64;       // A panel are adjacent (L2 reuse)

  // A staging coords: thread t loads A[m0 + t>>2][kk + (t&3)*8 .. +7]
  const int a_ml   = tid >> 2;
  const int a_k8   = tid & 3;
  const int a_slot = ((a_ml >> 5) * 2 + (a_k8 >> 1)) * 64
                   + ((a_ml & 31) + ((a_k8 & 1) << 5));
  const int a_row  = m0 + a_ml;

  f32x16 acc0 = {};
  f32x16 acc1 = {};

  const int K = NQ * Fi;
  for (int k0 = 0; k0 < K; k0 += 32) {
    const int q  = k0 / Fi;               // BK=32 divides Fi -> single source
    const int kk = k0 - q * Fi;
    const float* A = (q == 0) ? A0 : ((q == 1) ? A1 : A2);

    // ---- stage A tile (64x32 fp32 -> hi/lo bf16, fragment-linear) ----
    float av[8];
    if (a_row < N) {
      const float* ap = A + (size_t)a_row * Fi + (kk + (a_k8 << 3));
      vf4 v0 = *(const vf4*)ap;
      vf4 v1 = *(const vf4*)(ap + 4);
#pragma unroll
      for (int j = 0; j < 4; j++) { av[j] = v0[j]; av[4 + j] = v1[j]; }
    } else {
#pragma unroll
      for (int j = 0; j < 8; j++) av[j] = 0.f;
    }
    bf16x8 ahi, alo;
#pragma unroll
    for (int j = 0; j < 8; j++) {
      unsigned short h = f2bf(av[j]);
      ahi[j] = (short)h;
      alo[j] = (short)f2bf(av[j] - bf2f(h));
    }
    sAhi[a_slot] = ahi;
    sAlo[a_slot] = alo;

    // ---- stage B tile (32x128, fragment-linear; 2 slots per thread) ----
#pragma unroll
    for (int i = 0; i < 2; i++) {
      const int s  = tid + (i << 8);
      const int fb = s >> 6;
      const int lb = s & 63;
      const int ncol = n0 + ((fb >> 1) << 5) + (lb & 31);
      const int krow = q * Fi + kk + ((fb & 1) << 4) + ((lb >> 5) << 3);
      bf16x8 bhi;
      if (wflag) {
        const float* wp = (const float*)W + (size_t)krow * Fo + ncol;
        bf16x8 blo;
#pragma unroll
        for (int j = 0; j < 8; j++) {
          float wv = wp[(size_t)j * Fo];
          unsigned short h = f2bf(wv);
          bhi[j] = (short)h;
          blo[j] = (short)f2bf(wv - bf2f(h));
        }
        sBlo[s] = blo;
      } else {
        const unsigned short* wp = (const unsigned short*)W + (size_t)krow * Fo + ncol;
#pragma unroll
        for (int j = 0; j < 8; j++) bhi[j] = (short)wp[(size_t)j * Fo];
      }
      sBhi[s] = bhi;
    }
    __syncthreads();

    // ---- fragment loads (all lane-consecutive b128, conflict-free) ----
    const bf16x8 aH0 = sAhi[((wm << 1) + 0) * 64 + lane];
    const bf16x8 aH1 = sAhi[((wm << 1) + 1) * 64 + lane];
    const bf16x8 aL0 = sAlo[((wm << 1) + 0) * 64 + lane];
    const bf16x8 aL1 = sAlo[((wm << 1) + 1) * 64 + lane];
    const int bbase = (wn << 2) * 64 + lane;        // f = wn*4 + nf*2 + kc
    const bf16x8 b00 = sBhi[bbase];
    const bf16x8 b01 = sBhi[bbase + 64];
    const bf16x8 b10 = sBhi[bbase + 128];
    const bf16x8 b11 = sBhi[bbase + 192];

    acc0 = __builtin_amdgcn_mfma_f32_32x32x16_bf16(aH0, b00, acc0, 0, 0, 0);
    acc0 = __builtin_amdgcn_mfma_f32_32x32x16_bf16(aL0, b00, acc0, 0, 0, 0);
    acc0 = __builtin_amdgcn_mfma_f32_32x32x16_bf16(aH1, b01, acc0, 0, 0, 0);
    acc0 = __builtin_amdgcn_mfma_f32_32x32x16_bf16(aL1, b01, acc0, 0, 0, 0);
    acc1 = __builtin_amdgcn_mfma_f32_32x32x16_bf16(aH0, b10, acc1, 0, 0, 0);
    acc1 = __builtin_amdgcn_mfma_f32_32x32x16_bf16(aL0, b10, acc1, 0, 0, 0);
    acc1 = __builtin_amdgcn_mfma_f32_32x32x16_bf16(aH1, b11, acc1, 0, 0, 0);
    acc1 = __builtin_amdgcn_mfma_f32_32x32x16_bf16(aL1, b11, acc1, 0, 0, 0);
    if (wflag) {                    // fp32 weights need the B_lo correction
      const bf16x8 c00 = sBlo[bbase];
      const bf16x8 c01 = sBlo[bbase + 64];
      const bf16x8 c10 = sBlo[bbase + 128];
      const bf16x8 c11 = sBlo[bbase + 192];
      acc0 = __builtin_amdgcn_mfma_f32_32x32x16_bf16(aH0, c00, acc0, 0, 0, 0);
      acc0 = __builtin_amdgcn_mfma_f32_32x32x16_bf16(aH1, c01, acc0, 0, 0, 0);
      acc1 = __builtin_amdgcn_mfma_f32_32x32x16_bf16(aH0, c10, acc1, 0, 0, 0);
      acc1 = __builtin_amdgcn_mfma_f32_32x32x16_bf16(aH1, c11, acc1, 0, 0, 0);
    }
    __syncthreads();
  }

  // ---- epilogue: verified C/D mapping, bias + relu, dtype-dispatch ----
  auto epi = [&](const f32x16& acc, int nf) {
    const int ncol = n0 + (((wn << 1) + nf) << 5) + (lane & 31);
    const float bv = wflag ? ((const float*)bias)[ncol]
                           : bf2f(((const unsigned short*)bias)[ncol]);
#pragma unroll
    for (int r = 0; r < 16; r++) {
      const int m = m0 + (wm << 5) + (r & 3) + ((r >> 2) << 3) + ((lane >> 5) << 2);
      if (m < N) {
        float vv = acc[r] + bv;
        if (relu) vv = fmaxf(vv, 0.f);
        const size_t o = (size_t)m * Fo + ncol;
        if (outF)       outF[o]  = vv;
        else if (wflag) outB32[o] = vv;
        else            outB16[o] = f2bf(vv);
      }
    }
  };
  epi(acc0, 0);
  epi(acc1, 1);
}

// ---------------- host (kernel launches ONLY) ----------------

static size_t align256(size_t x) { return (x + 255) & ~(size_t)255; }

extern "C" void kernel_launch(void* const* d_in, const int* in_sizes, int n_in,
                              void* d_out, int out_size, void* d_ws, size_t ws_size,
                              hipStream_t stream) {
  const void* v    = d_in[0];
  const void* ei   = d_in[1];
  const void* W1   = d_in[2];
  const void* b1   = d_in[3];
  const void* W2   = d_in[4];
  const void* b2   = d_in[5];
  const void* W3   = d_in[6];
  const void* b3   = d_in[7];
  const void* Wmu  = d_in[8];
  const void* bmu  = d_in[9];
  const void* Wstd = d_in[10];
  const void* bstd = d_in[11];
  (void)n_in; (void)ws_size;

  const int N = in_sizes[0] / 128;   // 10000
  const int E = in_sizes[1] / 2;     // 160000

  // workspace carve-out
  char* base = (char*)d_ws;
  size_t off = 0;
  int*   eflag;  eflag  = (int*)  (base + off); off = align256(off + 4);
  int*   vflag;  vflag  = (int*)  (base + off); off = align256(off + 4);
  int*   rowi;   rowi   = (int*)  (base + off); off = align256(off + (size_t)E * 4);
  int*   coli;   coli   = (int*)  (base + off); off = align256(off + (size_t)E * 4);
  float* deg;    deg    = (float*)(base + off); off = align256(off + (size_t)N * 4);
  float* dis;    dis    = (float*)(base + off); off = align256(off + (size_t)N * 4);
  int*   cnt;    cnt    = (int*)  (base + off); off = align256(off + (size_t)N * 4);
  int*   colPtr; colPtr = (int*)  (base + off); off = align256(off + (size_t)(N + 1) * 4);
  int*   cursor; cursor = (int*)  (base + off); off = align256(off + (size_t)N * 4);
  int*   srcRow; srcRow = (int*)  (base + off); off = align256(off + (size_t)E * 4);
  float* srcW;   srcW   = (float*)(base + off); off = align256(off + (size_t)E * 4);
  float* xA;     xA     = (float*)(base + off); off = align256(off + (size_t)N * 256 * 4);
  float* xB;     xB     = (float*)(base + off); off = align256(off + (size_t)N * 512 * 4);
  float* tx1;    tx1    = (float*)(base + off); off = align256(off + (size_t)N * 256 * 4);
  float* tx2;    tx2    = (float*)(base + off); off = align256(off + (size_t)N * 256 * 4);

  unsigned short* outMu16  = (unsigned short*)d_out;
  unsigned short* outStd16 = outMu16 + (size_t)N * 256;
  float*          outMu32  = (float*)d_out;
  float*          outStd32 = outMu32 + (size_t)N * 256;

  // 1) sentinel: proves kernels execute at all (overwritten by heads below)
  k_sentinel<<<(out_size + 255) / 256, 256, 0, stream>>>((unsigned short*)d_out, out_size);

  // 2) dtype probes
  k_ftype<<<1, 256, 0, stream>>>((const unsigned*)v, 1024, vflag);
  k_etype<<<1, 256, 0, stream>>>((const unsigned*)ei, 2048, eflag);

  // 3) graph preprocessing
  k_zero<<<(N + 255) / 256, 256, 0, stream>>>(deg, cnt, N);
  k_decode<<<(E + 255) / 256, 256, 0, stream>>>(ei, eflag, E, N, rowi, coli, deg, cnt);
  k_dis<<<(N + 255) / 256, 256, 0, stream>>>(deg, dis, N);
  k_scan<<<1, 256, 0, stream>>>(cnt, colPtr, cursor, N);
  k_place<<<(E + 255) / 256, 256, 0, stream>>>(rowi, coli, dis, cursor, srcRow, srcW, E);
  k_convert<<<(N * 128 + 255) / 256, 256, 0, stream>>>(v, vflag, xA, N * 128);

  const int gM = (N + 63) / 64;   // 157 m-tiles of 64 rows

  // layer 1: Fi=128 -> Fo=128, x0=xA -> x1=xB
  k_prop<<<N, 128, 0, stream>>>(xA, nullptr, tx1, colPtr, srcRow, srcW, 128, 1.f, 0.f);
  k_prop<<<N, 128, 0, stream>>>(tx1, xA, tx2, colPtr, srcRow, srcW, 128, 2.f, -1.f);
  k_gemm_mfma<<<dim3(1, gM), 256, 0, stream>>>(xA, tx1, tx2, W1, b1, vflag,
                                               N, 128, 3, 128, xB, nullptr, nullptr, 1);

  // layer 2: Fi=128 -> Fo=256, x1=xB -> x2=xA
  k_prop<<<N, 128, 0, stream>>>(xB, nullptr, tx1, colPtr, srcRow, srcW, 128, 1.f, 0.f);
  k_prop<<<N, 128, 0, stream>>>(tx1, xB, tx2, colPtr, srcRow, srcW, 128, 2.f, -1.f);
  k_gemm_mfma<<<dim3(2, gM), 256, 0, stream>>>(xB, tx1, tx2, W2, b2, vflag,
                                               N, 128, 3, 256, xA, nullptr, nullptr, 1);

  // layer 3: Fi=256 -> Fo=512, x2=xA -> x3=xB
  k_prop<<<N, 256, 0, stream>>>(xA, nullptr, tx1, colPtr, srcRow, srcW, 256, 1.f, 0.f);
  k_prop<<<N, 256, 0, stream>>>(tx1, xA, tx2, colPtr, srcRow, srcW, 256, 2.f, -1.f);
  k_gemm_mfma<<<dim3(4, gM), 256, 0, stream>>>(xA, tx1, tx2, W3, b3, vflag,
                                               N, 256, 3, 512, xB, nullptr, nullptr, 1);

  // heads: x3 (N x 512) @ Wmu/Wstd (512 x 256) -> d_out in detected dtype
  k_gemm_mfma<<<dim3(2, gM), 256, 0, stream>>>(xB, nullptr, nullptr, Wmu, bmu, vflag,
                                               N, 512, 1, 256,
                                               nullptr, outMu16, outMu32, 0);
  k_gemm_mfma<<<dim3(2, gM), 256, 0, stream>>>(xB, nullptr, nullptr, Wstd, bstd, vflag,
                                               N, 512, 1, 256,
                                               nullptr, outStd16, outStd32, 0);
}

// Round 2
// 453.930 us; speedup vs baseline: 1.8041x; 1.1724x over previous
//
#include <hip/hip_runtime.h>
#include <hip/hip_bf16.h>

// ---------------- types & helpers ----------------

typedef __attribute__((ext_vector_type(8)))  short bf16x8;   // 8 bf16 = 4 VGPR
typedef __attribute__((ext_vector_type(16))) float f32x16;   // MFMA 32x32 acc

__device__ __forceinline__ unsigned short f2bf(float x) {    // RNE fp32->bf16
  union { float f; unsigned u; } c; c.f = x;
  return (unsigned short)((c.u + 0x7fffu + ((c.u >> 16) & 1u)) >> 16);
}
__device__ __forceinline__ float bf2f(unsigned short u) {    // exact bf16->fp32
  union { unsigned u; float f; } c; c.u = ((unsigned)u) << 16;
  return c.f;
}

// async global->LDS, 16B per lane; LDS dest = wave-uniform base + lane*16
__device__ __forceinline__ void gld16(const void* g, void* l) {
  __builtin_amdgcn_global_load_lds(
      (const __attribute__((address_space(1))) unsigned int*)g,
      (__attribute__((address_space(3))) unsigned int*)l, 16, 0, 0);
}

// ---------------- sentinel & dtype probes ----------------

__global__ void k_sentinel(unsigned short* __restrict__ out, int n) {
  int i = blockIdx.x * blockDim.x + threadIdx.x;
  if (i < n) out[i] = 0x3F00;
}

__global__ void k_ftype(const unsigned* __restrict__ p, int nwords, int* __restrict__ vflag) {
  __shared__ int red[256];
  int ok = 0;
  for (int i = threadIdx.x; i < nwords; i += 256) {
    unsigned lo = p[i] & 0xffffu;
    unsigned ef = (lo >> 7) & 0xffu;
    if (ef >= 115u && ef <= 140u) ok++;
  }
  red[threadIdx.x] = ok;
  __syncthreads();
  for (int s = 128; s > 0; s >>= 1) {
    if (threadIdx.x < s) red[threadIdx.x] += red[threadIdx.x + s];
    __syncthreads();
  }
  if (threadIdx.x == 0) *vflag = (red[0] < nwords / 2) ? 1 : 0;
}

__global__ void k_etype(const unsigned* __restrict__ p, int nwords, int* __restrict__ eflag) {
  __shared__ unsigned red[256];
  unsigned acc = 0;
  for (int i = threadIdx.x; i < nwords; i += 256)
    if (i & 1) acc |= p[i];
  red[threadIdx.x] = acc;
  __syncthreads();
  for (int s = 128; s > 0; s >>= 1) {
    if (threadIdx.x < s) red[threadIdx.x] |= red[threadIdx.x + s];
    __syncthreads();
  }
  if (threadIdx.x == 0) *eflag = (red[0] == 0u) ? 1 : 0;
}

// ---------------- weight pre-pack ----------------
// Pack W[K][Fo] into fragment-linear slots: slot s = (nt*KS + ks)*8 + fb,
// lane l, 8 bf16: element W[ks*32 + (fb&1)*16 + (l>>5)*8 + j][nt*128 + (fb>>1)*32 + (l&31)].
// Slot = 64 lanes x 16B, contiguous -> GEMM B-staging is one coalesced gld16.
__global__ void k_wpack(const void* __restrict__ W, const int* __restrict__ wflagp,
                        int K, int Fo, unsigned short* __restrict__ dstHi,
                        unsigned short* __restrict__ dstLo) {
  const int t = blockIdx.x * 256 + threadIdx.x;
  const int KS = K >> 5;
  const int total = (Fo >> 7) * KS * 8;
  const int s = t >> 6;
  if (s >= total) return;
  const int lane = t & 63;
  const int fb = s & 7;
  const int sk = s >> 3;
  const int ks = sk % KS;
  const int nt = sk / KS;
  const int col = (nt << 7) + ((fb >> 1) << 5) + (lane & 31);
  const int row = (ks << 5) + ((fb & 1) << 4) + ((lane >> 5) << 3);
  const int wflag = *wflagp;
  bf16x8 hi;
  if (wflag) {
    const float* Wf = (const float*)W;
    bf16x8 lo;
#pragma unroll
    for (int j = 0; j < 8; j++) {
      float wv = Wf[(size_t)(row + j) * Fo + col];
      unsigned short h = f2bf(wv);
      hi[j] = (short)h;
      lo[j] = (short)f2bf(wv - bf2f(h));
    }
    *(bf16x8*)(dstLo + (size_t)s * 512 + lane * 8) = lo;
  } else {
    const unsigned short* Wb = (const unsigned short*)W;
#pragma unroll
    for (int j = 0; j < 8; j++)
      hi[j] = (short)Wb[(size_t)(row + j) * Fo + col];
  }
  *(bf16x8*)(dstHi + (size_t)s * 512 + lane * 8) = hi;
}

// ---------------- preprocessing ----------------

__global__ void k_zero(float* __restrict__ deg, int* __restrict__ cnt, int n) {
  int i = blockIdx.x * blockDim.x + threadIdx.x;
  if (i < n) { deg[i] = 0.0f; cnt[i] = 0; }
}

__global__ void k_decode(const void* __restrict__ ei, const int* __restrict__ eflag,
                         int E, int N, int* __restrict__ rowi, int* __restrict__ coli,
                         float* __restrict__ deg, int* __restrict__ cnt) {
  int e = blockIdx.x * blockDim.x + threadIdx.x;
  if (e >= E) return;
  int f = *eflag;
  int r, c;
  if (f) {
    const long long* q = (const long long*)ei;
    r = (int)q[e]; c = (int)q[e + E];
  } else {
    const int* q = (const int*)ei;
    r = q[e]; c = q[e + E];
  }
  r = min(max(r, 0), N - 1);
  c = min(max(c, 0), N - 1);
  rowi[e] = r; coli[e] = c;
  atomicAdd(&deg[r], 1.0f);
  atomicAdd(&cnt[c], 1);
}

__global__ void k_dis(const float* __restrict__ deg, float* __restrict__ dis, int n) {
  int i = blockIdx.x * blockDim.x + threadIdx.x;
  if (i < n) {
    float d = deg[i];
    dis[i] = (d > 0.f) ? rsqrtf(d) : 0.f;
  }
}

// 1024-thread shuffle-based scan: 3 barriers per 1024-chunk (vs ~32 before).
__global__ __launch_bounds__(1024) void k_scan(const int* __restrict__ cnt,
                                               int* __restrict__ colPtr,
                                               int* __restrict__ cursor, int n) {
  __shared__ int ws[16];
  const int t = threadIdx.x;
  const int lane = t & 63;
  const int w = t >> 6;
  int carry = 0;
  for (int base = 0; base < n; base += 1024) {
    int i = base + t;
    int v = (i < n) ? cnt[i] : 0;
    int x = v;
#pragma unroll
    for (int off = 1; off < 64; off <<= 1) {
      int y = __shfl_up(x, off);
      if (lane >= off) x += y;
    }
    if (lane == 63) ws[w] = x;
    __syncthreads();
    if (w == 0) {
      int sv = (lane < 16) ? ws[lane] : 0;
#pragma unroll
      for (int off = 1; off < 16; off <<= 1) {
        int y = __shfl_up(sv, off);
        if (lane >= off) sv += y;
      }
      if (lane < 16) ws[lane] = sv;   // inclusive wave-sum prefix
    }
    __syncthreads();
    int woff = (w == 0) ? 0 : ws[w - 1];
    int incl = carry + woff + x;
    if (i < n) { colPtr[i + 1] = incl; cursor[i] = incl - v; }
    int tot = ws[15];
    __syncthreads();
    carry += tot;
  }
  if (t == 0) colPtr[0] = 0;
}

__global__ void k_place(const int* __restrict__ rowi, const int* __restrict__ coli,
                        const float* __restrict__ dis, int* __restrict__ cursor,
                        int* __restrict__ srcRow, float* __restrict__ srcW, int E) {
  int e = blockIdx.x * blockDim.x + threadIdx.x;
  if (e >= E) return;
  int r = rowi[e], c = coli[e];
  float wv = -dis[r] * dis[c];
  int pos = atomicAdd(&cursor[c], 1);
  srcRow[pos] = r;
  srcW[pos] = wv;
}

// v (bf16 or fp32) -> fp32 plane + hi/lo bf16 planes
__global__ void k_convert(const void* __restrict__ v, const int* __restrict__ vflag,
                          float* __restrict__ xf, unsigned short* __restrict__ xh,
                          unsigned short* __restrict__ xl, int n) {
  int i = blockIdx.x * blockDim.x + threadIdx.x;
  if (i >= n) return;
  float val;
  if (*vflag) val = ((const float*)v)[i];
  else        val = __bfloat162float(((const __hip_bfloat16*)v)[i]);
  xf[i] = val;
  unsigned short h = f2bf(val);
  xh[i] = h;
  xl[i] = f2bf(val - bf2f(h));
}

// ---------------- propagation ----------------
// out[c,:] = alpha * sum_{e: col=c} w_e * z[row_e,:] + beta*base[c,:]
// Also emits hi/lo bf16 split planes for the downstream MFMA GEMM.
__global__ void k_prop(const float* __restrict__ z, const float* __restrict__ base,
                       float* __restrict__ outF, unsigned short* __restrict__ outH,
                       unsigned short* __restrict__ outL,
                       const int* __restrict__ colPtr, const int* __restrict__ srcRow,
                       const float* __restrict__ srcW,
                       int F, float alpha, float beta) {
  const int c = blockIdx.x;
  const int f = threadIdx.x;
  const int s = colPtr[c];
  const int e = colPtr[c + 1];
  float acc = 0.f;
  for (int j = s; j < e; j++)
    acc = fmaf(srcW[j], z[(size_t)srcRow[j] * F + f], acc);
  float vv = alpha * acc;
  if (base != nullptr) vv = fmaf(beta, base[(size_t)c * F + f], vv);
  const size_t o = (size_t)c * F + f;
  if (outF != nullptr) outF[o] = vv;
  unsigned short h = f2bf(vv);
  outH[o] = h;
  outL[o] = f2bf(vv - bf2f(h));
}

// ---------------- MFMA GEMM ----------------
// C[N,Fo] = maybe_relu( [A0|A1|A2] @ W + b ), A pre-split hi/lo bf16 planes,
// W pre-packed fragment-linear (k_wpack). All staging via global_load_lds
// width 16 into fragment-linear LDS (lane-contiguous 16B slots).
// acc += A_hi*B_hi + A_lo*B_hi (+ A_hi*B_lo when W fp32).
// C/D mapping (verified): col = lane&31, row = (reg&3)+8*(reg>>2)+4*(lane>>5).
// LDS slots (1KB each): 0-3 A-hi, 4-7 A-lo, 8-15 B-hi, 16-23 B-lo.
__global__ __launch_bounds__(256, 4) void k_gemm_mfma(
    const unsigned short* __restrict__ a0h, const unsigned short* __restrict__ a0l,
    const unsigned short* __restrict__ a1h, const unsigned short* __restrict__ a1l,
    const unsigned short* __restrict__ a2h, const unsigned short* __restrict__ a2l,
    const unsigned short* __restrict__ packHi, const unsigned short* __restrict__ packLo,
    const void* __restrict__ bias, const int* __restrict__ wflagp,
    int N, int Fi, int NQ, int Fo,
    float* __restrict__ outF, unsigned short* __restrict__ outH,
    unsigned short* __restrict__ outL,
    unsigned short* __restrict__ outB16, float* __restrict__ outB32, int relu) {
  __shared__ bf16x8 sm[24 * 64];

  const int wflag = *wflagp;
  const int tid  = threadIdx.x;
  const int lane = tid & 63;
  const int w    = tid >> 6;
  const int wm   = w >> 1;
  const int wn   = w & 1;
  const int nt   = blockIdx.x;
  const int n0   = nt << 7;
  const int m0   = blockIdx.y << 6;
  const int KS   = (NQ * Fi) >> 5;

  // wave w stages A slot w: row = m0 + (w>>1)*32 + (l&31), k-chunk kc = w&1
  const int arow  = m0 + ((w >> 1) << 5) + (lane & 31);
  const int aeoff = ((w & 1) << 4) + ((lane >> 5) << 3);

  f32x16 acc0 = {}, acc1 = {};

  int q = 0, kk = 0;
  for (int ks = 0; ks < KS; ks++) {
    const unsigned short* Ah = (q == 0) ? a0h : (q == 1 ? a1h : a2h);
    const unsigned short* Al = (q == 0) ? a0l : (q == 1 ? a1l : a2l);
    const size_t aoff = (size_t)arow * Fi + kk + aeoff;
    gld16(Ah + aoff, &sm[w * 64]);
    gld16(Al + aoff, &sm[(4 + w) * 64]);
    const size_t boff = (size_t)(nt * KS + ks) * 8 * 512 + lane * 8;
    gld16(packHi + boff + (size_t)(2 * w)     * 512, &sm[(8 + 2 * w) * 64]);
    gld16(packHi + boff + (size_t)(2 * w + 1) * 512, &sm[(9 + 2 * w) * 64]);
    if (wflag) {
      gld16(packLo + boff + (size_t)(2 * w)     * 512, &sm[(16 + 2 * w) * 64]);
      gld16(packLo + boff + (size_t)(2 * w + 1) * 512, &sm[(17 + 2 * w) * 64]);
    }
    __syncthreads();   // drains vmcnt (global_load_lds) before frag reads

    const bf16x8 aH0 = sm[(wm * 2) * 64 + lane];
    const bf16x8 aH1 = sm[(wm * 2 + 1) * 64 + lane];
    const bf16x8 aL0 = sm[(4 + wm * 2) * 64 + lane];
    const bf16x8 aL1 = sm[(4 + wm * 2 + 1) * 64 + lane];
    const int bb = (8 + wn * 4) * 64 + lane;
    const bf16x8 b00 = sm[bb];
    const bf16x8 b01 = sm[bb + 64];
    const bf16x8 b10 = sm[bb + 128];
    const bf16x8 b11 = sm[bb + 192];

    acc0 = __builtin_amdgcn_mfma_f32_32x32x16_bf16(aH0, b00, acc0, 0, 0, 0);
    acc0 = __builtin_amdgcn_mfma_f32_32x32x16_bf16(aL0, b00, acc0, 0, 0, 0);
    acc0 = __builtin_amdgcn_mfma_f32_32x32x16_bf16(aH1, b01, acc0, 0, 0, 0);
    acc0 = __builtin_amdgcn_mfma_f32_32x32x16_bf16(aL1, b01, acc0, 0, 0, 0);
    acc1 = __builtin_amdgcn_mfma_f32_32x32x16_bf16(aH0, b10, acc1, 0, 0, 0);
    acc1 = __builtin_amdgcn_mfma_f32_32x32x16_bf16(aL0, b10, acc1, 0, 0, 0);
    acc1 = __builtin_amdgcn_mfma_f32_32x32x16_bf16(aH1, b11, acc1, 0, 0, 0);
    acc1 = __builtin_amdgcn_mfma_f32_32x32x16_bf16(aL1, b11, acc1, 0, 0, 0);
    if (wflag) {
      const int cb = (16 + wn * 4) * 64 + lane;
      const bf16x8 c00 = sm[cb];
      const bf16x8 c01 = sm[cb + 64];
      const bf16x8 c10 = sm[cb + 128];
      const bf16x8 c11 = sm[cb + 192];
      acc0 = __builtin_amdgcn_mfma_f32_32x32x16_bf16(aH0, c00, acc0, 0, 0, 0);
      acc0 = __builtin_amdgcn_mfma_f32_32x32x16_bf16(aH1, c01, acc0, 0, 0, 0);
      acc1 = __builtin_amdgcn_mfma_f32_32x32x16_bf16(aH0, c10, acc1, 0, 0, 0);
      acc1 = __builtin_amdgcn_mfma_f32_32x32x16_bf16(aH1, c11, acc1, 0, 0, 0);
    }
    __syncthreads();

    kk += 32;
    if (kk == Fi) { kk = 0; q++; }
  }

  // ---- epilogue ----
  auto epi = [&](const f32x16& acc, int nf) {
    const int ncol = n0 + (((wn << 1) + nf) << 5) + (lane & 31);
    const float bv = wflag ? ((const float*)bias)[ncol]
                           : bf2f(((const unsigned short*)bias)[ncol]);
#pragma unroll
    for (int r = 0; r < 16; r++) {
      const int m = m0 + (wm << 5) + (r & 3) + ((r >> 2) << 3) + ((lane >> 5) << 2);
      if (m < N) {
        float vv = acc[r] + bv;
        if (relu) vv = fmaxf(vv, 0.f);
        const size_t o = (size_t)m * Fo + ncol;
        if (outF) outF[o] = vv;
        if (outH) {
          unsigned short h = f2bf(vv);
          outH[o] = h;
          outL[o] = f2bf(vv - bf2f(h));
        }
        if (outB16) {
          if (wflag) outB32[o] = vv;
          else       outB16[o] = f2bf(vv);
        }
      }
    }
  };
  epi(acc0, 0);
  epi(acc1, 1);
}

// ---------------- host (kernel launches ONLY) ----------------

static size_t align256(size_t x) { return (x + 255) & ~(size_t)255; }

extern "C" void kernel_launch(void* const* d_in, const int* in_sizes, int n_in,
                              void* d_out, int out_size, void* d_ws, size_t ws_size,
                              hipStream_t stream) {
  const void* v    = d_in[0];
  const void* ei   = d_in[1];
  const void* W1   = d_in[2];
  const void* b1   = d_in[3];
  const void* W2   = d_in[4];
  const void* b2   = d_in[5];
  const void* W3   = d_in[6];
  const void* b3   = d_in[7];
  const void* Wmu  = d_in[8];
  const void* bmu  = d_in[9];
  const void* Wstd = d_in[10];
  const void* bstd = d_in[11];
  (void)n_in; (void)ws_size;

  const int N = in_sizes[0] / 128;   // 10000
  const int E = in_sizes[1] / 2;     // 160000
  const size_t NP = (size_t)N + 64;  // row padding: OOB A-tile rows stay mapped

  typedef unsigned short u16;
  char* base = (char*)d_ws;
  size_t off = 0;
  auto carve = [&](size_t bytes) { void* p = base + off; off = align256(off + bytes); return p; };

  int*   eflag  = (int*)  carve(4);
  int*   vflag  = (int*)  carve(4);
  int*   rowi   = (int*)  carve((size_t)E * 4);
  int*   coli   = (int*)  carve((size_t)E * 4);
  float* deg    = (float*)carve((size_t)N * 4);
  float* dis    = (float*)carve((size_t)N * 4);
  int*   cnt    = (int*)  carve((size_t)N * 4);
  int*   colPtr = (int*)  carve((size_t)(N + 1) * 4);
  int*   cursor = (int*)  carve((size_t)N * 4);
  int*   srcRow = (int*)  carve((size_t)E * 4);
  float* srcW   = (float*)carve((size_t)E * 4);

  // weight packs (hi/lo)
  u16* pW1h = (u16*)carve((size_t)384 * 128 * 2);
  u16* pW1l = (u16*)carve((size_t)384 * 128 * 2);
  u16* pW2h = (u16*)carve((size_t)384 * 256 * 2);
  u16* pW2l = (u16*)carve((size_t)384 * 256 * 2);
  u16* pW3h = (u16*)carve((size_t)768 * 512 * 2);
  u16* pW3l = (u16*)carve((size_t)768 * 512 * 2);
  u16* pWmh = (u16*)carve((size_t)512 * 256 * 2);
  u16* pWml = (u16*)carve((size_t)512 * 256 * 2);
  u16* pWsh = (u16*)carve((size_t)512 * 256 * 2);
  u16* pWsl = (u16*)carve((size_t)512 * 256 * 2);

  // activation planes (X: layer input, Y: layer output; ping-pong)
  float* Xf = (float*)carve(NP * 256 * 4);
  u16*   Xh = (u16*)  carve(NP * 256 * 2);
  u16*   Xl = (u16*)  carve(NP * 256 * 2);
  float* Yf = (float*)carve(NP * 128 * 4);
  u16*   Yh = (u16*)  carve(NP * 512 * 2);
  u16*   Yl = (u16*)  carve(NP * 512 * 2);
  float* t1f = (float*)carve(NP * 256 * 4);
  u16*   t1h = (u16*)  carve(NP * 256 * 2);
  u16*   t1l = (u16*)  carve(NP * 256 * 2);
  u16*   t2h = (u16*)  carve(NP * 256 * 2);
  u16*   t2l = (u16*)  carve(NP * 256 * 2);

  u16*   outMu16  = (u16*)d_out;
  u16*   outStd16 = outMu16 + (size_t)N * 256;
  float* outMu32  = (float*)d_out;
  float* outStd32 = outMu32 + (size_t)N * 256;

  // 1) sentinel
  k_sentinel<<<(out_size + 255) / 256, 256, 0, stream>>>((u16*)d_out, out_size);

  // 2) dtype probes
  k_ftype<<<1, 256, 0, stream>>>((const unsigned*)v, 1024, vflag);
  k_etype<<<1, 256, 0, stream>>>((const unsigned*)ei, 2048, eflag);

  // 3) weight pre-pack (once per launch; trivial cost)
  k_wpack<<< 24, 256, 0, stream>>>(W1,   vflag, 384, 128, pW1h, pW1l);
  k_wpack<<< 48, 256, 0, stream>>>(W2,   vflag, 384, 256, pW2h, pW2l);
  k_wpack<<<192, 256, 0, stream>>>(W3,   vflag, 768, 512, pW3h, pW3l);
  k_wpack<<< 64, 256, 0, stream>>>(Wmu,  vflag, 512, 256, pWmh, pWml);
  k_wpack<<< 64, 256, 0, stream>>>(Wstd, vflag, 512, 256, pWsh, pWsl);

  // 4) graph preprocessing
  k_zero<<<(N + 255) / 256, 256, 0, stream>>>(deg, cnt, N);
  k_decode<<<(E + 255) / 256, 256, 0, stream>>>(ei, eflag, E, N, rowi, coli, deg, cnt);
  k_dis<<<(N + 255) / 256, 256, 0, stream>>>(deg, dis, N);
  k_scan<<<1, 1024, 0, stream>>>(cnt, colPtr, cursor, N);
  k_place<<<(E + 255) / 256, 256, 0, stream>>>(rowi, coli, dis, cursor, srcRow, srcW, E);
  k_convert<<<(N * 128 + 255) / 256, 256, 0, stream>>>(v, vflag, Xf, Xh, Xl, N * 128);

  const int gM = (N + 63) / 64;   // 157 m-tiles

  // layer 1: Fi=128 -> Fo=128, X -> Y
  k_prop<<<N, 128, 0, stream>>>(Xf, nullptr, t1f, t1h, t1l, colPtr, srcRow, srcW, 128, 1.f, 0.f);
  k_prop<<<N, 128, 0, stream>>>(t1f, Xf, nullptr, t2h, t2l, colPtr, srcRow, srcW, 128, 2.f, -1.f);
  k_gemm_mfma<<<dim3(1, gM), 256, 0, stream>>>(Xh, Xl, t1h, t1l, t2h, t2l, pW1h, pW1l,
                                               b1, vflag, N, 128, 3, 128,
                                               Yf, Yh, Yl, nullptr, nullptr, 1);

  // layer 2: Fi=128 -> Fo=256, Y -> X
  k_prop<<<N, 128, 0, stream>>>(Yf, nullptr, t1f, t1h, t1l, colPtr, srcRow, srcW, 128, 1.f, 0.f);
  k_prop<<<N, 128, 0, stream>>>(t1f, Yf, nullptr, t2h, t2l, colPtr, srcRow, srcW, 128, 2.f, -1.f);
  k_gemm_mfma<<<dim3(2, gM), 256, 0, stream>>>(Yh, Yl, t1h, t1l, t2h, t2l, pW2h, pW2l,
                                               b2, vflag, N, 128, 3, 256,
                                               Xf, Xh, Xl, nullptr, nullptr, 1);

  // layer 3: Fi=256 -> Fo=512, X -> Y (hi/lo only; no one reads fp32 x3)
  k_prop<<<N, 256, 0, stream>>>(Xf, nullptr, t1f, t1h, t1l, colPtr, srcRow, srcW, 256, 1.f, 0.f);
  k_prop<<<N, 256, 0, stream>>>(t1f, Xf, nullptr, t2h, t2l, colPtr, srcRow, srcW, 256, 2.f, -1.f);
  k_gemm_mfma<<<dim3(4, gM), 256, 0, stream>>>(Xh, Xl, t1h, t1l, t2h, t2l, pW3h, pW3l,
                                               b3, vflag, N, 256, 3, 512,
                                               nullptr, Yh, Yl, nullptr, nullptr, 1);

  // heads: x3 (N x 512 hi/lo) @ Wmu/Wstd -> d_out in detected dtype
  k_gemm_mfma<<<dim3(2, gM), 256, 0, stream>>>(Yh, Yl, nullptr, nullptr, nullptr, nullptr,
                                               pWmh, pWml, bmu, vflag, N, 512, 1, 256,
                                               nullptr, nullptr, nullptr, outMu16, outMu32, 0);
  k_gemm_mfma<<<dim3(2, gM), 256, 0, stream>>>(Yh, Yl, nullptr, nullptr, nullptr, nullptr,
                                               pWsh, pWsl, bstd, vflag, N, 512, 1, 256,
                                               nullptr, nullptr, nullptr, outStd16, outStd32, 0);
}